// Round 6
// baseline (478.478 us; speedup 1.0000x reference)
//
#include <hip/hip_runtime.h>

#define B_ROWS 1024
#define D_DIM  512
#define C_CLS  100000
#define N_TILES 782       // ceil(100000/128) (fallback kernel)
#define GRID_NJ 98        // fallback grid helper
#define NT256 391         // ceil(100000/256)
#define GRID_256 1564     // 4 M-tiles * 391 N-tiles

typedef unsigned short u16;
typedef __attribute__((ext_vector_type(8))) short bf16x8;
typedef __attribute__((ext_vector_type(4))) float f32x4;

__device__ __forceinline__ u16 f2bf(float f) {
  unsigned u = __float_as_uint(f);
  u += 0x7fffu + ((u >> 16) & 1u);   // round-to-nearest-even
  return (u16)(u >> 16);
}

// pack 8 fp32 -> 8 bf16 (RTZ high-16) via v_perm_b32 (fallback path only)
__device__ __forceinline__ bf16x8 pack8(float4 a, float4 b) {
  union { bf16x8 v; unsigned u[4]; } r;
  r.u[0] = __builtin_amdgcn_perm(__float_as_uint(a.y), __float_as_uint(a.x), 0x07060302u);
  r.u[1] = __builtin_amdgcn_perm(__float_as_uint(a.w), __float_as_uint(a.z), 0x07060302u);
  r.u[2] = __builtin_amdgcn_perm(__float_as_uint(b.y), __float_as_uint(b.x), 0x07060302u);
  r.u[3] = __builtin_amdgcn_perm(__float_as_uint(b.w), __float_as_uint(b.z), 0x07060302u);
  return r.v;
}

__device__ __forceinline__ void gll16(const void* g, void* l) {
  __builtin_amdgcn_global_load_lds(
      (const __attribute__((address_space(1))) unsigned int*)g,
      (__attribute__((address_space(3))) unsigned int*)l, 16, 0, 0);
}

// ---------------- fast path: prep (features + weights -> normalized bf16) ---
__global__ __launch_bounds__(256) void prep_kernel(
    const float* __restrict__ feat, const float* __restrict__ wt,
    u16* __restrict__ fn, u16* __restrict__ wb, float* __restrict__ psum)
{
  const int lane  = threadIdx.x & 63;
  const int wid   = blockIdx.x * 4 + (threadIdx.x >> 6);
  const int nw    = gridDim.x * 4;
  const int total = B_ROWS + C_CLS;
  for (int row = wid; row < total; row += 2 * nw) {
    const int rowb  = row + nw;
    const bool hasb = rowb < total;
    const float* sa = (row < B_ROWS) ? feat + (size_t)row * D_DIM
                                     : wt + (size_t)(row - B_ROWS) * D_DIM;
    u16* da = (row < B_ROWS) ? fn + (size_t)row * D_DIM
                             : wb + (size_t)(row - B_ROWS) * D_DIM;
    const float* sb = sa;
    u16* db = da;
    if (hasb) {
      sb = (rowb < B_ROWS) ? feat + (size_t)rowb * D_DIM
                           : wt + (size_t)(rowb - B_ROWS) * D_DIM;
      db = (rowb < B_ROWS) ? fn + (size_t)rowb * D_DIM
                           : wb + (size_t)(rowb - B_ROWS) * D_DIM;
    }
    const float4 a0 = ((const float4*)sa)[2 * lane];
    const float4 a1 = ((const float4*)sa)[2 * lane + 1];
    const float4 b0 = ((const float4*)sb)[2 * lane];
    const float4 b1 = ((const float4*)sb)[2 * lane + 1];
    float ssa = a0.x*a0.x + a0.y*a0.y + a0.z*a0.z + a0.w*a0.w
              + a1.x*a1.x + a1.y*a1.y + a1.z*a1.z + a1.w*a1.w;
    float ssb = b0.x*b0.x + b0.y*b0.y + b0.z*b0.z + b0.w*b0.w
              + b1.x*b1.x + b1.y*b1.y + b1.z*b1.z + b1.w*b1.w;
#pragma unroll
    for (int m = 1; m < 64; m <<= 1) {
      ssa += __shfl_xor(ssa, m);
      ssb += __shfl_xor(ssb, m);
    }
    const float inva = 1.0f / fmaxf(sqrtf(ssa), 1e-12f);
    const float invb = 1.0f / fmaxf(sqrtf(ssb), 1e-12f);
    union { bf16x8 v; u16 e[8]; } oa, ob;
    oa.e[0] = f2bf(a0.x * inva); oa.e[1] = f2bf(a0.y * inva);
    oa.e[2] = f2bf(a0.z * inva); oa.e[3] = f2bf(a0.w * inva);
    oa.e[4] = f2bf(a1.x * inva); oa.e[5] = f2bf(a1.y * inva);
    oa.e[6] = f2bf(a1.z * inva); oa.e[7] = f2bf(a1.w * inva);
    ((bf16x8*)da)[lane] = oa.v;
    if (hasb) {
      ob.e[0] = f2bf(b0.x * invb); ob.e[1] = f2bf(b0.y * invb);
      ob.e[2] = f2bf(b0.z * invb); ob.e[3] = f2bf(b0.w * invb);
      ob.e[4] = f2bf(b1.x * invb); ob.e[5] = f2bf(b1.y * invb);
      ob.e[6] = f2bf(b1.z * invb); ob.e[7] = f2bf(b1.w * invb);
      ((bf16x8*)db)[lane] = ob.v;
    }
    if (row < B_ROWS && lane == 0) psum[row] = 0.0f;
  }
}

// ---------------- fast path: 256x256 / BK=64 8-wave 4-phase-per-K-tile GEMM -
// T3+T4+T5 structure. 512 thr = 8 waves (2M x 4N); per-wave output 128x64.
// LDS: As/Ws = [2 buf][2 half][128 rows][64 k] bf16 (64 KB each).
// Per K-tile c (buf = c&1), 4 phases, each {ds_read ; stage 1 half-tile ;
// barrier ; lgkmcnt(0)+sched_barrier ; setprio(1) 16 MFMA setprio(0) ; barrier}.
// Stage schedule (derived WAR-safe: W slots free after end-P2, A after end-P3):
//   P1: (c+1).A1   P3: (c+2).W0,(c+2).W1   P4: (c+2).A0 ; vmcnt(6)
// vmcnt(6) = 3 half-tiles in flight; guarantees tile c+1 fully landed at its
// P1 reads (barrier after vmcnt makes it block-wide).
__global__ __launch_bounds__(512, 2) void arc_gemm_256(
    const u16* __restrict__ fn, const u16* __restrict__ wb,
    const int* __restrict__ targets, float* __restrict__ psum,
    float* __restrict__ tlogit)
{
  __shared__ u16 As[2 * 2 * 128 * 64];   // [buf][half][row][k]
  __shared__ u16 Ws[2 * 2 * 128 * 64];
  __shared__ int tg[256];

  const int tid = threadIdx.x;
  // bijective XCD swizzle, nwg = 1564 = 8*195 + 4  (m204 variant)
  const int orig = blockIdx.x;
  const int xcd  = orig & 7;
  const int wgid = (xcd < 4 ? xcd * 196 : 784 + (xcd - 4) * 195) + (orig >> 3);
  const int tile_m = (wgid & 3) << 8;
  const int tile_n = (wgid >> 2) << 8;

  if (tid < 256) tg[tid] = targets[tile_m + tid];

  const int lane = tid & 63;
  const int wid  = tid >> 6;
  const int wm = wid >> 2;                 // 0..1  (M half)
  const int wn = wid & 3;                  // 0..3  (N quarter)
  const int quad = lane >> 4, l15 = lane & 15;

  // ---- staging constants: thread t covers row t>>3 (of 64), 16B chunk t&7,
  // XOR-swizzled on the GLOBAL source (LDS dest linear): slot s of row r
  // holds global chunk s ^ (r&7)  -> read side spreads banks, 0-conflict.
  const int rowoff = tid >> 3;             // 0..63
  const int chunkX = (tid & 7) ^ (rowoff & 7);
  const size_t aBase = (size_t)(tile_m + rowoff) * D_DIM + chunkX * 8;
  const unsigned wo00 = (unsigned)min(tile_n +   0 +  0 + rowoff, C_CLS - 1) * D_DIM + chunkX * 8;
  const unsigned wo01 = (unsigned)min(tile_n +   0 + 64 + rowoff, C_CLS - 1) * D_DIM + chunkX * 8;
  const unsigned wo10 = (unsigned)min(tile_n + 128 +  0 + rowoff, C_CLS - 1) * D_DIM + chunkX * 8;
  const unsigned wo11 = (unsigned)min(tile_n + 128 + 64 + rowoff, C_CLS - 1) * D_DIM + chunkX * 8;
  const int ldst = tid * 8;                // u16 offset of this thread's 16B

  auto stA = [&](int buf, int h, int kt) {
    gll16(fn + aBase + (size_t)(h * 128) * D_DIM + kt * 64,
          As + buf * 16384 + h * 8192 + ldst);
    gll16(fn + aBase + (size_t)(h * 128 + 64) * D_DIM + kt * 64,
          As + buf * 16384 + h * 8192 + 4096 + ldst);
  };
  auto stW = [&](int buf, int h, int kt) {
    gll16(wb + (h ? wo10 : wo00) + kt * 64,
          Ws + buf * 16384 + h * 8192 + ldst);
    gll16(wb + (h ? wo11 : wo01) + kt * 64,
          Ws + buf * 16384 + h * 8192 + 4096 + ldst);
  };

  // ---- read-side: row within half = frag*16 + l15 (row&7 == l15&7);
  // slot(ks,quad) = (ks*4+quad) ^ (l15&7); ks1 offset = ks0 ^ 32 (u16).
  const int sw0 = (quad ^ (l15 & 7)) * 8;
  const int rdA = wm * 8192 + l15 * 64 + sw0;
  const int rdW = (wn >> 1) * 8192 + (wn & 1) * 4096 + l15 * 64 + sw0;

  f32x4 acc[8][4] = {};
  bf16x8 af[4][2], wf[4][2];

  auto mfmaQ = [&](int mh, int ks) {
    __builtin_amdgcn_s_setprio(1);
#pragma unroll
    for (int m = 0; m < 4; m++)
#pragma unroll
      for (int n = 0; n < 4; n++)
        acc[mh * 4 + m][n] = __builtin_amdgcn_mfma_f32_16x16x32_bf16(
            af[m][ks], wf[n][ks], acc[mh * 4 + m][n], 0, 0, 0);
    __builtin_amdgcn_s_setprio(0);
  };

#define PBAR() __builtin_amdgcn_s_barrier()
#define LGKM0_FENCE() do { \
    asm volatile("s_waitcnt lgkmcnt(0)" ::: "memory"); \
    __builtin_amdgcn_sched_barrier(0); } while (0)

  // prologue: tiles 0 (all), 1.W0, 1.W1, 1.A0  (14 loads); vmcnt(6) -> tile0 in
  stA(0, 0, 0); stA(0, 1, 0); stW(0, 0, 0); stW(0, 1, 0);
  stW(1, 0, 1); stW(1, 1, 1); stA(1, 0, 1);
  asm volatile("s_waitcnt vmcnt(6)" ::: "memory");
  PBAR();

  for (int c = 0; c < 8; ++c) {
    const int bo = (c & 1) * 16384;
    // P1: read A(mh0, both ks) + W(ks0); stage (c+1).A1
#pragma unroll
    for (int m = 0; m < 4; m++) {
      af[m][0] = *(const bf16x8*)(As + bo + rdA + m * 1024);
      af[m][1] = *(const bf16x8*)(As + bo + (rdA ^ 32) + m * 1024);
    }
#pragma unroll
    for (int n = 0; n < 4; n++)
      wf[n][0] = *(const bf16x8*)(Ws + bo + rdW + n * 1024);
    if (c < 7) stA((c + 1) & 1, 1, c + 1);
    PBAR(); LGKM0_FENCE();
    mfmaQ(0, 0);
    PBAR();
    // P2: read W(ks1)
#pragma unroll
    for (int n = 0; n < 4; n++)
      wf[n][1] = *(const bf16x8*)(Ws + bo + (rdW ^ 32) + n * 1024);
    PBAR(); LGKM0_FENCE();
    mfmaQ(0, 1);
    PBAR();
    // P3: reload A(mh1, both ks); stage (c+2).W0,W1 (slots freed end-P2)
#pragma unroll
    for (int m = 0; m < 4; m++) {
      af[m][0] = *(const bf16x8*)(As + bo + rdA + (m + 4) * 1024);
      af[m][1] = *(const bf16x8*)(As + bo + (rdA ^ 32) + (m + 4) * 1024);
    }
    if (c < 6) { stW(c & 1, 0, c + 2); stW(c & 1, 1, c + 2); }
    PBAR(); LGKM0_FENCE();
    mfmaQ(1, 0);
    PBAR();
    // P4: stage (c+2).A0 (A slots freed end-P3); counted vmcnt, never 0
    if (c < 6) {
      stA(c & 1, 0, c + 2);
      asm volatile("s_waitcnt vmcnt(6)" ::: "memory");
    } else if (c == 6) {
      asm volatile("s_waitcnt vmcnt(0)" ::: "memory");   // tail drain
    }
    PBAR();
    mfmaQ(1, 1);
    PBAR();
  }

  // ---- fused ArcFace epilogue; acc IS the cosine ----
  const float Sc   = 30.0f;
  const float COSM = 0.9553364891256060f;
  const float SINM = 0.2955202066613396f;
  const float THc  = -0.9553364891256060f;
  const float MMc  = 0.0886560619984019f;

  float* pr = (float*)As;   // 4 x 256 partials; As dead after K-loop

#pragma unroll
  for (int m = 0; m < 8; m++) {
#pragma unroll
    for (int reg = 0; reg < 4; reg++) {
      const int bl = wm * 128 + m * 16 + quad * 4 + reg;   // C/D row = M index
      const int b = tile_m + bl;
      const int tgt = tg[bl];
      float s = 0.0f;
#pragma unroll
      for (int n = 0; n < 4; n++) {
        const int cc = tile_n + wn * 64 + n * 16 + l15;    // C/D col = N index
        const float cosv = acc[m][n][reg];
        float logit = Sc * cosv;
        if (cc == tgt) {
          const float sine = sqrtf(fmaxf(1.0f - cosv * cosv, 0.0f));
          float phi = cosv * COSM - sine * SINM;
          phi = (cosv > THc) ? phi : (cosv - MMc);
          logit = Sc * phi;
          tlogit[b] = logit;   // unique owner of (b, tgt)
        }
        s += (cc < C_CLS) ? __expf(logit - 30.0f) : 0.0f;  // mask pad cols
      }
      s += __shfl_xor(s, 1);
      s += __shfl_xor(s, 2);
      s += __shfl_xor(s, 4);
      s += __shfl_xor(s, 8);
      if (l15 == 0) pr[wn * 256 + bl] = s;
    }
  }
  __syncthreads();
  if (tid < 256)
    atomicAdd(psum + tile_m + tid,
              pr[tid] + pr[256 + tid] + pr[512 + tid] + pr[768 + tid]);
}

// ---------------- fallback path (round-0 proven kernels) --------------------
__global__ void norm_feat_kernel(const float* __restrict__ in,
                                 u16* __restrict__ out,
                                 float* __restrict__ psum)
{
  const int row  = blockIdx.x * 4 + (threadIdx.x >> 6);
  const int lane = threadIdx.x & 63;
  const float4* r = (const float4*)(in + (size_t)row * D_DIM);
  float4 v0 = r[lane];
  float4 v1 = r[lane + 64];
  float ss = v0.x*v0.x + v0.y*v0.y + v0.z*v0.z + v0.w*v0.w
           + v1.x*v1.x + v1.y*v1.y + v1.z*v1.z + v1.w*v1.w;
#pragma unroll
  for (int m = 1; m < 64; m <<= 1) ss += __shfl_xor(ss, m);
  const float inv = 1.0f / fmaxf(sqrtf(ss), 1e-12f);
  ushort4 o0, o1;
  o0.x = f2bf(v0.x * inv); o0.y = f2bf(v0.y * inv);
  o0.z = f2bf(v0.z * inv); o0.w = f2bf(v0.w * inv);
  o1.x = f2bf(v1.x * inv); o1.y = f2bf(v1.y * inv);
  o1.z = f2bf(v1.z * inv); o1.w = f2bf(v1.w * inv);
  ushort4* orow = (ushort4*)(out + (size_t)row * D_DIM);
  orow[lane]      = o0;
  orow[lane + 64] = o1;
  if (lane == 0) psum[row] = 0.0f;
}

__global__ __launch_bounds__(256, 4) void arc_gemm_raw(
    const u16* __restrict__ fn, const float* __restrict__ wt,
    const int* __restrict__ targets, float* __restrict__ psum,
    float* __restrict__ tlogit)
{
  __shared__ u16 As[128 * 32];
  __shared__ u16 Ws[128 * 32];
  __shared__ int tg[128];
  __shared__ float winv[128];

  const int tid = threadIdx.x;
  const int bx  = blockIdx.x;
  const int xcd = bx & 7;
  const int l   = bx >> 3;
  const int tile_ni = (l >> 3) * 8 + xcd;
  if (tile_ni >= N_TILES) return;
  const int tile_m = (l & 7) << 7;
  const int tile_n = tile_ni << 7;

  if (tid < 128) tg[tid] = targets[tile_m + tid];

  const int wave = tid >> 6, lane = tid & 63;
  const int wm = wave >> 1, wno = wave & 1;
  const int quad = lane >> 4, l15 = lane & 15;

  f32x4 acc[4][4] = {};

  const int srow   = tid >> 2;
  const int schunk = (tid & 3) ^ ((tid >> 3) & 3);
  const u16* Ag = fn + (size_t)(tile_m + srow) * D_DIM + schunk * 8;
  u16* Asd0 = As + tid * 8;
  u16* Asd1 = As + 2048 + tid * 8;
  const int wr0 = tile_n + srow;
  const int wr1 = wr0 + 64;
  const float* Wg0 = wt + (size_t)min(wr0, C_CLS - 1) * D_DIM + schunk * 8;
  const float* Wg1 = wt + (size_t)min(wr1, C_CLS - 1) * D_DIM + schunk * 8;
  u16* Wsd0 = Ws + tid * 8;
  u16* Wsd1 = Ws + 2048 + tid * 8;

  const int rsw = (quad ^ ((l15 >> 1) & 3)) * 8;
  const u16* ApA = As + (wm * 64 + l15) * 32 + rsw;
  const u16* ApW = Ws + (wno * 64 + l15) * 32 + rsw;

  float ssq0 = 0.0f, ssq1 = 0.0f;

  for (int k0 = 0; k0 < D_DIM; k0 += 32) {
    const float4 wa = *(const float4*)(Wg0 + k0);
    const float4 wb2 = *(const float4*)(Wg0 + k0 + 4);
    const float4 wc = *(const float4*)(Wg1 + k0);
    const float4 wd = *(const float4*)(Wg1 + k0 + 4);
    gll16(Ag + k0, Asd0);
    gll16(Ag + 64 * D_DIM + k0, Asd1);
    ssq0 += wa.x*wa.x + wa.y*wa.y + wa.z*wa.z + wa.w*wa.w
          + wb2.x*wb2.x + wb2.y*wb2.y + wb2.z*wb2.z + wb2.w*wb2.w;
    ssq1 += wc.x*wc.x + wc.y*wc.y + wc.z*wc.z + wc.w*wc.w
          + wd.x*wd.x + wd.y*wd.y + wd.z*wd.z + wd.w*wd.w;
    *(bf16x8*)Wsd0 = pack8(wa, wb2);
    *(bf16x8*)Wsd1 = pack8(wc, wd);
    __syncthreads();
    bf16x8 af[4], wf[4];
#pragma unroll
    for (int r = 0; r < 4; r++) af[r] = *(const bf16x8*)(ApA + r * 16 * 32);
#pragma unroll
    for (int r = 0; r < 4; r++) wf[r] = *(const bf16x8*)(ApW + r * 16 * 32);
#pragma unroll
    for (int rm = 0; rm < 4; rm++)
#pragma unroll
      for (int rn = 0; rn < 4; rn++)
        acc[rm][rn] = __builtin_amdgcn_mfma_f32_16x16x32_bf16(
            af[rm], wf[rn], acc[rm][rn], 0, 0, 0);
    __syncthreads();
  }

  ssq0 += __shfl_xor(ssq0, 1); ssq0 += __shfl_xor(ssq0, 2);
  ssq1 += __shfl_xor(ssq1, 1); ssq1 += __shfl_xor(ssq1, 2);
  if ((tid & 3) == 0) {
    winv[srow]      = 1.0f / fmaxf(sqrtf(ssq0), 1e-12f);
    winv[srow + 64] = 1.0f / fmaxf(sqrtf(ssq1), 1e-12f);
  }
  __syncthreads();

  float wiv[4];
#pragma unroll
  for (int rn = 0; rn < 4; rn++) wiv[rn] = winv[wno * 64 + rn * 16 + l15];

  const float Sc   = 30.0f;
  const float COSM = 0.9553364891256060f;
  const float SINM = 0.2955202066613396f;
  const float THc  = -0.9553364891256060f;
  const float MMc  = 0.0886560619984019f;

#pragma unroll
  for (int rm = 0; rm < 4; rm++) {
#pragma unroll
    for (int reg = 0; reg < 4; reg++) {
      const int bl = wm * 64 + rm * 16 + quad * 4 + reg;
      const int b = tile_m + bl;
      const int tgt = tg[bl];
      float s = 0.0f;
#pragma unroll
      for (int rn = 0; rn < 4; rn++) {
        const int c = tile_n + wno * 64 + rn * 16 + l15;
        const float cosv = acc[rm][rn][reg] * wiv[rn];
        float logit = Sc * cosv;
        if (c == tgt) {
          const float sine = sqrtf(fmaxf(1.0f - cosv * cosv, 0.0f));
          float phi = cosv * COSM - sine * SINM;
          phi = (cosv > THc) ? phi : (cosv - MMc);
          logit = Sc * phi;
          tlogit[b] = logit;
        }
        s += (c < C_CLS) ? __expf(logit - 30.0f) : 0.0f;
      }
      s += __shfl_xor(s, 1);
      s += __shfl_xor(s, 2);
      s += __shfl_xor(s, 4);
      s += __shfl_xor(s, 8);
      if (l15 == 0) atomicAdd(psum + b, s);
    }
  }
}

__global__ void finalize_loss(const float* __restrict__ psum,
                              const float* __restrict__ tlogit,
                              float* __restrict__ out)
{
  const int tid = threadIdx.x;
  float s = 0.0f;
  for (int i = tid; i < B_ROWS; i += 256)
    s += 30.0f + logf(psum[i]) - tlogit[i];
#pragma unroll
  for (int m = 1; m < 64; m <<= 1) s += __shfl_xor(s, m);
  __shared__ float red[4];
  if ((tid & 63) == 0) red[tid >> 6] = s;
  __syncthreads();
  if (tid == 0) out[0] = (red[0] + red[1] + red[2] + red[3]) * (1.0f / B_ROWS);
}

extern "C" void kernel_launch(void* const* d_in, const int* in_sizes, int n_in,
                              void* d_out, int out_size, void* d_ws, size_t ws_size,
                              hipStream_t stream) {
  const float* feat = (const float*)d_in[0];
  const float* wt   = (const float*)d_in[1];
  const int*   tgt  = (const int*)d_in[2];
  float* out = (float*)d_out;
  char* ws = (char*)d_ws;

  const size_t fn_bytes = (size_t)B_ROWS * D_DIM * 2;        // 1 MB
  const size_t wb_bytes = (size_t)C_CLS * D_DIM * 2;         // 102.4 MB
  const size_t tail     = 2 * (size_t)B_ROWS * sizeof(float);

  if (ws_size >= fn_bytes + wb_bytes + tail) {
    // fast path: W pre-normalized to bf16 in workspace
    u16* fn = (u16*)ws;
    u16* wb = (u16*)(ws + fn_bytes);
    float* psum = (float*)(ws + fn_bytes + wb_bytes);
    float* tlogit = psum + B_ROWS;
    prep_kernel<<<2048, 256, 0, stream>>>(feat, wt, fn, wb, psum);
    arc_gemm_256<<<GRID_256, 512, 0, stream>>>(fn, wb, tgt, psum, tlogit);
    finalize_loss<<<1, 256, 0, stream>>>(psum, tlogit, out);
  } else {
    // fallback: proven round-0 path (~1 MB workspace)
    u16* fn = (u16*)ws;
    float* psum = (float*)(ws + fn_bytes);
    float* tlogit = psum + B_ROWS;
    norm_feat_kernel<<<B_ROWS / 4, 256, 0, stream>>>(feat, fn, psum);
    arc_gemm_raw<<<GRID_NJ * 8 * 8, 256, 0, stream>>>(fn, wt, tgt, psum, tlogit);
    finalize_loss<<<1, 256, 0, stream>>>(psum, tlogit, out);
  }
}